// Round 6
// baseline (349.306 us; speedup 1.0000x reference)
//
#include <hip/hip_runtime.h>

// ---------------------------------------------------------------------------
// LinearAttention: out = (featmap(xWq+bq) @ [K^T V]) / (q . sum K + eps) @ Wo + bo
// featmap(t) = elu(t)+1 = t>0 ? t+1 : exp(t)
// B=4, S=4096, D_MODEL=1024, H=16, DK=64. Inputs fp32; compute in bf16 MFMA.
// R12: (a) kvk_mfma v2 — grid (4,64) (1 block/CU), per-block 1024 s; cross-
//     wave reduce via 64KB LDS 'red' buffer then 16 coalesced atomics/thread:
//     8.4M -> 1M fp32 atomicAdds (R11 had 32 partial-adds per kvT cell).
//     (b) conv_x + conv_w merged into one dispatch (block-uniform branch).
//     gemm0/gemm1 (R8 2-barrier loop + M-slab XCD swizzle, 108 us measured)
//     and attn unchanged — isolate the kv/dispatch delta.
// ---------------------------------------------------------------------------

typedef __bf16 bf16;
typedef float  f32x4  __attribute__((ext_vector_type(4)));
typedef short  s16x8  __attribute__((ext_vector_type(8)));   // 8 bf16 = 4 VGPRs (MFMA A/B frag)
typedef bf16   bf16x4 __attribute__((ext_vector_type(4)));

#define BATCH 4
#define SEQ   4096
#define DM    1024
#define NH    16
#define DK    64
#define MROWS (BATCH*SEQ)            // 16384
#define EPSV  1e-6f
#define NXB   (MROWS*DM/1024)        // 16384 conv_x blocks

// async 16B global->LDS DMA. LDS dest is wave-uniform base; HW writes
// base + lane*16.
__device__ __forceinline__ void async_cp16(const bf16* g, bf16* l) {
  __builtin_amdgcn_global_load_lds((const __attribute__((address_space(1))) void*)g,
                                   (__attribute__((address_space(3))) void*)l,
                                   16, 0, 0);
}

// ------------------------------------------------- conv_fused (x + Wt) ------
// bid < NXB: fp32->bf16 cast of x (1024 floats/block).
// else: Wt[z*1024+n][k] = Wz[k][n] 64x64 tile transpose via LDS.
__global__ __launch_bounds__(256) void conv_fused_kernel(const float* __restrict__ x,
                                                         bf16* __restrict__ xb,
                                                         const float* __restrict__ W0,
                                                         const float* __restrict__ W1,
                                                         const float* __restrict__ W2,
                                                         const float* __restrict__ W3,
                                                         bf16* __restrict__ Wt) {
  __shared__ bf16 tt[64][72];                         // [n][k], pad 72
  const int bid = blockIdx.x;
  const int tid = threadIdx.x;
  if (bid < NXB) {                                    // ---- conv_x part
    int i = (bid * 256 + tid) * 4;
    float4 f = *reinterpret_cast<const float4*>(x + i);
    bf16x4 o;
    o[0] = (bf16)f.x; o[1] = (bf16)f.y; o[2] = (bf16)f.z; o[3] = (bf16)f.w;
    *reinterpret_cast<bf16x4*>(xb + i) = o;
    return;
  }
  // ---- conv_w part (1024 blocks: z 0..3, 16x16 tiles)
  const int b2 = bid - NXB;
  const int z = b2 >> 8;
  const float* W = (z == 0) ? W0 : (z == 1) ? W1 : (z == 2) ? W2 : W3;
  const int n0 = (b2 & 15) * 64, k0 = ((b2 >> 4) & 15) * 64;
#pragma unroll
  for (int i = 0; i < 4; ++i) {                       // 1024 float4 chunks (64x16)
    const int c = tid + i * 256;
    const int krow = c >> 4, nch = c & 15;
    float4 f = *reinterpret_cast<const float4*>(W + (size_t)(k0 + krow) * DM + n0 + nch * 4);
    tt[nch * 4 + 0][krow] = (bf16)f.x;
    tt[nch * 4 + 1][krow] = (bf16)f.y;
    tt[nch * 4 + 2][krow] = (bf16)f.z;
    tt[nch * 4 + 3][krow] = (bf16)f.w;
  }
  __syncthreads();
#pragma unroll
  for (int i = 0; i < 2; ++i) {                       // 512 chunks: 64 rows x 8x16B
    const int c = tid + i * 256;
    const int nrow = c >> 3, kch = c & 7;
    *reinterpret_cast<uint4*>(Wt + (size_t)(z * DM + n0 + nrow) * DM + k0 + kch * 8) =
        *reinterpret_cast<const uint4*>(&tt[nrow][kch * 8]);
  }
}

// ------------------------------------------------------------------ GEMM ----
// C[M,N] = A[M,K] * Bt[N,K]^T, K=1024. 256x256 tile, 8 waves (2Mx4N), BK=64.
// R8 2-barrier-per-tile main loop. M-slab XCD swizzle.
// MODE 0: part0 -> Qb (featmap, ldc), part1 -> KT transposed (featmap),
//         part2 -> VT transposed. MODE 1: bias -> fp32 out.
template <int MODE>
__global__ __launch_bounds__(512, 2) void gemm_bf16(const bf16* __restrict__ A,
                                                    const bf16* __restrict__ Bt,
                                                    void* __restrict__ Cout, int ldc,
                                                    const float* __restrict__ b0,
                                                    const float* __restrict__ b1,
                                                    const float* __restrict__ b2,
                                                    bf16* __restrict__ kt,
                                                    bf16* __restrict__ vt) {
  constexpr int K  = 1024;
  constexpr int BK = 64;
  constexpr int NT = K / BK;                          // 16 K-tiles
  __shared__ __align__(16) char smem[131072];         // A:2x32K | B:2x32K (dbuf)

  const int tid  = threadIdx.x;
  const int wv   = tid >> 6, lane = tid & 63;
  const int quad = lane >> 4, l16 = lane & 15;
  const int swk  = l16 & 7;                           // read-side swizzle key

  // M-slab XCD swizzle: hw wgid w -> XCD (w&7) owns M-tiles 8k..8k+7
  // (4MB A-slab, L2-resident). Bijective: w = k + 8*(bx*8 + (by&7)).
  const int w = blockIdx.y * gridDim.x + blockIdx.x;
  const int j = w >> 3;
  const int bm0 = (((w & 7) << 3) + (j & 7)) << 8;    // M-tile (64 total)
  const int bn0 = (j >> 3) << 8;                      // N-tile

  const int wm = wv >> 2;                             // 0..1 -> A half (128 rows)
  const int wn = wv & 3;                              // 0..3 -> B 64-row group

  f32x4 acc[8][4] = {};
  s16x8 af[4][2];                                     // A quad frags [mi][ks]
  s16x8 bq[2][2][2];                                  // B frags [qn][ni][ks]

  const int srow = wv * 8 + (lane >> 3);
  const int scol = ((lane & 7) ^ (lane >> 3)) * 8;    // bf16 elements
  const bf16* Ag = A  + (size_t)(bm0 + srow) * K + scol;
  const bf16* Bg = Bt + (size_t)(bn0 + srow) * K + scol;
  const int sbase = wv * 1024;                        // wave-uniform LDS byte off

#define STAGE_A(t_, h_) do {                                                   \
    const bf16* g_ = Ag + (size_t)((h_) * 128) * K + (t_) * BK;                \
    char* l_ = smem + ((t_) & 1) * 32768 + (h_) * 16384 + sbase;               \
    async_cp16(g_, (bf16*)l_);                                                 \
    async_cp16(g_ + (size_t)64 * K, (bf16*)(l_ + 8192));                       \
  } while (0)
#define STAGE_B(t_, h_) do {                                                   \
    const bf16* g_ = Bg + (size_t)((h_) * 128) * K + (t_) * BK;                \
    char* l_ = smem + 65536 + ((t_) & 1) * 32768 + (h_) * 16384 + sbase;       \
    async_cp16(g_, (bf16*)l_);                                                 \
    async_cp16(g_ + (size_t)64 * K, (bf16*)(l_ + 8192));                       \
  } while (0)
#define LDA(pb_, qm_) do {                                                     \
    const char* ab_ = smem + (pb_) * 32768 +                                   \
        (size_t)(wm * 128 + (qm_) * 64 + l16) * 128;                           \
    _Pragma("unroll") for (int mi = 0; mi < 4; ++mi)                           \
      _Pragma("unroll") for (int ks = 0; ks < 2; ++ks)                         \
        af[mi][ks] = *reinterpret_cast<const s16x8*>(                          \
            ab_ + mi * 2048 + (((ks * 4 + quad) ^ swk) << 4));                 \
  } while (0)
#define LDB(pb_, qn_) do {                                                     \
    const char* bb_ = smem + 65536 + (pb_) * 32768 +                           \
        (size_t)(wn * 64 + (qn_) * 32 + l16) * 128;                            \
    _Pragma("unroll") for (int ni = 0; ni < 2; ++ni)                           \
      _Pragma("unroll") for (int ks = 0; ks < 2; ++ks)                         \
        bq[qn_][ni][ks] = *reinterpret_cast<const s16x8*>(                     \
            bb_ + ni * 2048 + (((ks * 4 + quad) ^ swk) << 4));                 \
  } while (0)
#define MFMA_Q(qm_, qn_) do {                                                  \
    _Pragma("unroll") for (int mi = 0; mi < 4; ++mi)                           \
      _Pragma("unroll") for (int ni = 0; ni < 2; ++ni)                         \
        _Pragma("unroll") for (int ks = 0; ks < 2; ++ks)                       \
          acc[(qm_) * 4 + mi][(qn_) * 2 + ni] =                                \
              __builtin_amdgcn_mfma_f32_16x16x32_bf16(                         \
                  af[mi][ks], bq[qn_][ni][ks],                                 \
                  acc[(qm_) * 4 + mi][(qn_) * 2 + ni], 0, 0, 0);               \
  } while (0)

  // prologue: tile0 full (8 ops) + tile1 h0 (4 ops); wait tile0 landed.
  STAGE_B(0, 0); STAGE_A(0, 0); STAGE_B(0, 1); STAGE_A(0, 1);
  STAGE_B(1, 0); STAGE_A(1, 0);
  asm volatile("s_waitcnt vmcnt(4)");                 // oldest 8 (tile0) retired
  __builtin_amdgcn_s_barrier();
  __builtin_amdgcn_sched_barrier(0);
  LDA(0, 0); LDB(0, 0); LDB(0, 1);                    // pre-reads tile0
  __builtin_amdgcn_sched_barrier(0);

#pragma unroll 2
  for (int t = 0; t < NT; ++t) {
    const int p = t & 1;
    // ---- cluster 0: quadrants (0,0),(0,1) on A0; prefetch B-h1(t+1) -> p^1
    if (t + 1 < NT) STAGE_B(t + 1, 1);
    asm volatile("s_waitcnt lgkmcnt(0)");
    __builtin_amdgcn_sched_barrier(0);
    __builtin_amdgcn_s_setprio(1);
    MFMA_Q(0, 0); MFMA_Q(0, 1);
    __builtin_amdgcn_s_setprio(0);
    LDA(p, 1);                                        // A1 reads run under other waves' MFMA
    __builtin_amdgcn_sched_barrier(0);
    // ---- cluster 1: quadrants (1,0),(1,1) on A1; prefetch A-h1(t+1) -> p^1
    if (t + 1 < NT) STAGE_A(t + 1, 1);
    asm volatile("s_waitcnt lgkmcnt(0)");
    __builtin_amdgcn_sched_barrier(0);
    __builtin_amdgcn_s_setprio(1);
    MFMA_Q(1, 0); MFMA_Q(1, 1);
    __builtin_amdgcn_s_setprio(0);
    __builtin_amdgcn_s_barrier();                     // all reads of buffer p done
    __builtin_amdgcn_sched_barrier(0);
    if (t + 2 < NT) { STAGE_B(t + 2, 0); STAGE_A(t + 2, 0); }  // -> p (safe)
    if (t + 1 < NT) {
      if (t + 2 < NT) asm volatile("s_waitcnt vmcnt(4)");  // all t+1 landed
      else            asm volatile("s_waitcnt vmcnt(0)");  // tail drain
      __builtin_amdgcn_s_barrier();                   // everyone's t+1 stages visible
      __builtin_amdgcn_sched_barrier(0);
      LDA(p ^ 1, 0); LDB(p ^ 1, 0); LDB(p ^ 1, 1);    // pre-reads tile t+1
      __builtin_amdgcn_sched_barrier(0);
    }
  }

  // epilogue: per-wave 16 KB LDS slice (no cross-wave sync; last tile's
  // post-cluster-1 barrier guarantees all waves drained their LDS reads).
  // D layout: col = l16 (N side), row = quad*4 + reg (M side).
  if (MODE == 0) {
    const int part = bn0 >> 10;                       // 0=q 1=k 2=v
    if (part == 0) {
      // Q: normal orientation -> Qb [16384][1024] bf16
      bf16* C = (bf16*)Cout;
      bf16 (*Cw)[64] = (bf16(*)[64])(smem + wv * 16384);
#pragma unroll
      for (int ni = 0; ni < 4; ++ni) {
        const int n_l = ni * 16 + l16;
        const float bias = b0[bn0 + wn * 64 + n_l];
#pragma unroll
        for (int mi = 0; mi < 8; ++mi)
#pragma unroll
          for (int r = 0; r < 4; ++r) {
            float v = acc[mi][ni][r] + bias;
            v = (v > 0.f) ? (v + 1.f) : __expf(v);    // elu+1
            const int row = mi * 16 + quad * 4 + r;
            Cw[row][n_l ^ ((row & 7) << 3)] = (bf16)v;
          }
      }
#pragma unroll
      for (int i = 0; i < 16; ++i) {                  // coalesced 16B stores
        const int row = i * 8 + (lane >> 3), ch = lane & 7;
        *reinterpret_cast<uint4*>(C + (size_t)(bm0 + wm * 128 + row) * ldc +
                                  bn0 + wn * 64 + ch * 8) =
            *reinterpret_cast<const uint4*>(&Cw[row][(ch ^ (row & 7)) * 8]);
      }
    } else {
      // K/V: transposed -> T[bh][d 0..63][s], per-wave LDS transpose.
      bf16* T = (part == 1) ? kt : vt;
      const float* bp = (part == 1) ? b1 : b2;
      const int b  = bm0 >> 12;                       // batch (no straddle)
      const int h  = ((bn0 & 1023) >> 6) + wn;        // wave's 64 cols = 1 head
      const int s_loc = (bm0 & 4095) + wm * 128;
      bf16* base = T + (size_t)(b * 16 + h) * 64 * 4096 + s_loc;
      char* sl = smem + wv * 16384;                   // [64 d][128 s] bf16, XOR-16B swz
#pragma unroll
      for (int ni = 0; ni < 4; ++ni) {
        const int d = ni * 16 + l16;
        const float bias = bp[(bn0 + wn * 64 + d) & 1023];
#pragma unroll
        for (int mi = 0; mi < 8; ++mi) {
          bf16x4 o;
#pragma unroll
          for (int r = 0; r < 4; ++r) {
            float v = acc[mi][ni][r] + bias;
            if (part == 1) v = (v > 0.f) ? (v + 1.f) : __expf(v);  // K featmap
            o[r] = (bf16)v;
          }
          const int sb = mi * 32 + quad * 8;          // byte offset of s*2 (8B-aligned)
          *reinterpret_cast<uint2*>(sl + d * 256 + (sb ^ ((d & 7) << 4))) =
              *reinterpret_cast<const uint2*>(&o);
        }
      }
      // per-wave slice: no barrier. Coalesced rows: d-row = 128 s = 256 B.
#pragma unroll
      for (int i = 0; i < 16; ++i) {
        const int d = i * 4 + (lane >> 4), ch = l16;  // 16B chunk = 8 s
        const uint4 val = *reinterpret_cast<const uint4*>(
            sl + d * 256 + ((ch * 16) ^ ((d & 7) << 4)));
        *reinterpret_cast<uint4*>(base + (size_t)d * 4096 + ch * 8) = val;
      }
    }
  } else {
    float* C = (float*)Cout;
    float (*Cwf)[64] = (float(*)[64])(smem + wv * 16384);
#pragma unroll
    for (int h = 0; h < 2; ++h) {                     // two 64-row passes
#pragma unroll
      for (int ni = 0; ni < 4; ++ni) {
        const int n_l = ni * 16 + l16;
        const float bias = b0[bn0 + wn * 64 + n_l];
#pragma unroll
        for (int mi = 0; mi < 4; ++mi)
#pragma unroll
          for (int r = 0; r < 4; ++r) {
            const int row = mi * 16 + quad * 4 + r;
            Cwf[row][n_l ^ ((row & 7) << 2)] = acc[h * 4 + mi][ni][r] + bias;
          }
      }
#pragma unroll
      for (int i = 0; i < 16; ++i) {                  // coalesced float4 stores
        const int row = i * 4 + (lane >> 4), ch = lane & 15;
        *reinterpret_cast<float4*>(C + (size_t)(bm0 + wm * 128 + h * 64 + row) * ldc +
                                   bn0 + wn * 64 + ch * 4) =
            *reinterpret_cast<const float4*>(&Cwf[row][(ch ^ (row & 7)) * 4]);
      }
    }
  }
#undef STAGE_A
#undef STAGE_B
#undef LDA
#undef LDB
#undef MFMA_Q
}

// -------------------------------------------------------------- kvk_mfma ----
// kvT[bh][e][d] += sum_s V[s,e]*K[s,d] via MFMA on transposed operands:
// A = VT[bh] rows (e, s-major), Bt = KT[bh] rows (d, s-major) -> D[e,d].
// grid (4,64) = 1 block/CU; block covers 1024 s (8 chunks of 128); waves
// k-slice-split per chunk; cross-wave reduce via LDS 'red' then 16 coalesced
// atomics/thread (1M total, was 8.4M). ksum folded into K staging.
__global__ __launch_bounds__(256) void kvk_mfma_kernel(const bf16* __restrict__ KT,
                                                       const bf16* __restrict__ VT,
                                                       float* __restrict__ kvT,
                                                       float* __restrict__ ksum) {
  __shared__ bf16 Ks[64][136];       // [d][s], pad 136
  __shared__ bf16 Vs[64][136];       // [e][s]
  __shared__ float red[4][4096];     // per-wave partials [wv][e*64+d]
  const int bh = blockIdx.y;
  const int tid = threadIdx.x;
  const int wv = tid >> 6, lane = tid & 63;
  const int quad = lane >> 4, l16 = lane & 15;
  const size_t tb = (size_t)bh * 64 * 4096;
  const int s0b = blockIdx.x * 1024;

  f32x4 acc[4][4] = {};
  float ksp[4] = {};                 // partial ksum for rows (tid>>4)+16i

  for (int cc = 0; cc < 8; ++cc) {
    const int s0 = s0b + cc * 128;
    __syncthreads();                 // prev-iter LDS reads done before restage
#pragma unroll
    for (int i = 0; i < 4; ++i) {
      const int c = tid + i * 256;
      const int row = c >> 4, ch = c & 15;
      const size_t go = tb + (size_t)row * 4096 + s0 + ch * 8;
      uint4 kk = *reinterpret_cast<const uint4*>(KT + go);
      *reinterpret_cast<uint4*>(&Ks[row][ch * 8]) = kk;
      *reinterpret_cast<uint4*>(&Vs[row][ch * 8]) =
          *reinterpret_cast<const uint4*>(VT + go);
      const bf16* kp = reinterpret_cast<const bf16*>(&kk);
      float t = 0.f;
#pragma unroll
      for (int jj = 0; jj < 8; ++jj) t += (float)kp[jj];
      ksp[i] += t;
    }
    __syncthreads();
    const int kb = wv * 32 + quad * 8;   // wave k-slice + frag quad offset
    s16x8 vfr[4], kfr[4];
#pragma unroll
    for (int mi = 0; mi < 4; ++mi) {
      vfr[mi] = *reinterpret_cast<const s16x8*>(&Vs[mi * 16 + l16][kb]);
      kfr[mi] = *reinterpret_cast<const s16x8*>(&Ks[mi * 16 + l16][kb]);
    }
#pragma unroll
    for (int mi = 0; mi < 4; ++mi)
#pragma unroll
      for (int ni = 0; ni < 4; ++ni)
        acc[mi][ni] = __builtin_amdgcn_mfma_f32_16x16x32_bf16(vfr[mi], kfr[ni],
                                                              acc[mi][ni], 0, 0, 0);
  }
  // cross-wave reduce: D layout row(e)=quad*4+r (+16mi), col(d)=l16 (+16ni)
#pragma unroll
  for (int mi = 0; mi < 4; ++mi)
#pragma unroll
    for (int ni = 0; ni < 4; ++ni)
#pragma unroll
      for (int r = 0; r < 4; ++r)
        red[wv][(mi * 16 + quad * 4 + r) * 64 + ni * 16 + l16] = acc[mi][ni][r];
  __syncthreads();
#pragma unroll
  for (int jj = 0; jj < 4; ++jj) {   // thread sums 16 cells (4 x float4)
    const int c0 = tid * 16 + jj * 4;
    const float4 s0 = *reinterpret_cast<const float4*>(&red[0][c0]);
    const float4 s1 = *reinterpret_cast<const float4*>(&red[1][c0]);
    const float4 s2 = *reinterpret_cast<const float4*>(&red[2][c0]);
    const float4 s3 = *reinterpret_cast<const float4*>(&red[3][c0]);
    atomicAdd(&kvT[tb / 64 + c0 + 0], s0.x + s1.x + s2.x + s3.x);
    atomicAdd(&kvT[tb / 64 + c0 + 1], s0.y + s1.y + s2.y + s3.y);
    atomicAdd(&kvT[tb / 64 + c0 + 2], s0.z + s1.z + s2.z + s3.z);
    atomicAdd(&kvT[tb / 64 + c0 + 3], s0.w + s1.w + s2.w + s3.w);
  }
  // ksum: 16-lane groups share row-set {g+16i}, g = tid>>4
#pragma unroll
  for (int i = 0; i < 4; ++i)
#pragma unroll
    for (int o = 8; o > 0; o >>= 1)
      ksp[i] += __shfl_down(ksp[i], o, 16);
  if (l16 == 0) {
    const int g = tid >> 4;
#pragma unroll
    for (int i = 0; i < 4; ++i)
      atomicAdd(&ksum[bh * 64 + g + 16 * i], ksp[i]);
  }
}

// ------------------------------------------------------------------ attn ----
// ATT[b,s, h*64+e] = (sum_d q[s,d]*kvT[e,d]) / (q[s,:].ksum + eps)   (bf16 out)
// MFMA: P^T[e,s] = kvT(A) @ q(Bt). Q from dense Qb [16384][1024].
__global__ __launch_bounds__(256) void attn_kernel(const bf16* __restrict__ Qb,
                                                   const float* __restrict__ kvT,
                                                   const float* __restrict__ ksum,
                                                   bf16* __restrict__ ATT) {
  __shared__ bf16 qs[128][72];       // [s][d], pad 72
  __shared__ bf16 kvs[64][72];       // [e][d] bf16
  __shared__ bf16 Ps[128][72];       // [s][e] scaled result
  __shared__ float zr[128];
  __shared__ float kss[64];
  const int bh = blockIdx.y;
  const int b = bh >> 4, h = bh & 15;
  const int s0 = blockIdx.x * 128;
  const int tid = threadIdx.x, wave = tid >> 6, lane = tid & 63;
  const int quad = lane >> 4, l16 = lane & 15;
  const size_t base = (size_t)b * SEQ * DM;
  const int colQ = h * 64;

#pragma unroll
  for (int i = 0; i < 4; ++i) {      // stage q tile 128x64
    const int c = tid + i * 256;
    const int row = c >> 3, off = (c & 7) * 8;
    *reinterpret_cast<uint4*>(&qs[row][off]) =
        *reinterpret_cast<const uint4*>(Qb + base + (size_t)(s0 + row) * DM + colQ + off);
  }
  const float* kvg = kvT + (size_t)bh * 4096;
#pragma unroll
  for (int i = 0; i < 4; ++i) {      // stage kvT 64x64 fp32 -> bf16
    const int c = tid + i * 256;
    const int row = c >> 4, off = (c & 15) * 4;
    float4 f = *reinterpret_cast<const float4*>(kvg + row * 64 + off);
    bf16x4 o;
    o[0] = (bf16)f.x; o[1] = (bf16)f.y; o[2] = (bf16)f.z; o[3] = (bf16)f.w;
    *reinterpret_cast<bf16x4*>(&kvs[row][off]) = o;
  }
  if (tid < 64) kss[tid] = ksum[bh * 64 + tid];
  __syncthreads();

  if (tid < 128) {                   // zr = 1/(q.ksum + eps) per row
    float z = 0.f;
#pragma unroll
    for (int d = 0; d < 64; d += 4) {
      bf16x4 q4 = *reinterpret_cast<const bf16x4*>(&qs[tid][d]);
      z += (float)q4[0] * kss[d] + (float)q4[1] * kss[d + 1] +
           (float)q4[2] * kss[d + 2] + (float)q4[3] * kss[d + 3];
    }
    zr[tid] = 1.0f / (z + EPSV);
  }
  __syncthreads();

  const int wn = wave * 32;
  f32x4 pacc[4][2] = {};
#pragma unroll
  for (int ks = 0; ks < 2; ++ks) {
    s16x8 af[4], bf2[2];
#pragma unroll
    for (int mi = 0; mi < 4; ++mi)
      af[mi] = *reinterpret_cast<const s16x8*>(&kvs[mi * 16 + l16][ks * 32 + quad * 8]);
#pragma unroll
    for (int ni = 0; ni < 2; ++ni)
      bf2[ni] = *reinterpret_cast<const s16x8*>(&qs[wn + ni * 16 + l16][ks * 32 + quad * 8]);
#pragma unroll
    for (int mi = 0; mi < 4; ++mi)
#pragma unroll
      for (int ni = 0; ni < 2; ++ni)
        pacc[mi][ni] = __builtin_amdgcn_mfma_f32_16x16x32_bf16(af[mi], bf2[ni],
                                                               pacc[mi][ni], 0, 0, 0);
  }
#pragma unroll
  for (int ni = 0; ni < 2; ++ni) {
    const int s = wn + ni * 16 + l16;
    const float zi = zr[s];
#pragma unroll
    for (int mi = 0; mi < 4; ++mi) {
      bf16x4 o;
#pragma unroll
      for (int r = 0; r < 4; ++r) o[r] = (bf16)(pacc[mi][ni][r] * zi);
      *reinterpret_cast<bf16x4*>(&Ps[s][mi * 16 + quad * 4]) = o;
    }
  }
  __syncthreads();
#pragma unroll
  for (int i = 0; i < 4; ++i) {      // coalesced 16B stores
    const int c = tid + i * 256;
    const int row = c >> 3, ch = c & 7;
    *reinterpret_cast<uint4*>(ATT + ((size_t)b * SEQ + s0 + row) * DM + h * 64 + ch * 8) =
        *reinterpret_cast<const uint4*>(&Ps[row][ch * 8]);
  }
}

// ---------------------------------------------------------------- launch ----
extern "C" void kernel_launch(void* const* d_in, const int* in_sizes, int n_in,
                              void* d_out, int out_size, void* d_ws, size_t ws_size,
                              hipStream_t stream) {
  const float* x  = (const float*)d_in[0];
  const float* Wq = (const float*)d_in[1];
  const float* bq = (const float*)d_in[2];
  const float* Wk = (const float*)d_in[3];
  const float* bk = (const float*)d_in[4];
  const float* Wv = (const float*)d_in[5];
  const float* bv = (const float*)d_in[6];
  const float* Wo = (const float*)d_in[7];
  const float* bo = (const float*)d_in[8];
  float* out = (float*)d_out;

  char* ws = (char*)d_ws;
  bf16*  Xb   = (bf16*)ws;   ws += (size_t)MROWS * DM * 2;        // 32 MB
  bf16*  Wt   = (bf16*)ws;   ws += (size_t)4 * DM * DM * 2;       // 8 MB (qkv^T + o^T)
  bf16*  Qb   = (bf16*)ws;   ws += (size_t)MROWS * DM * 2;        // 32 MB
  bf16*  KT   = (bf16*)ws;   ws += (size_t)64 * 64 * 4096 * 2;    // 32 MB [bh][d][s]
  bf16*  VT   = (bf16*)ws;   ws += (size_t)64 * 64 * 4096 * 2;    // 32 MB [bh][e][s]
  bf16*  ATT  = (bf16*)ws;   ws += (size_t)MROWS * DM * 2;        // 32 MB
  float* kvT  = (float*)ws;  ws += (size_t)64 * 4096 * 4;         // 1 MB [bh][e][d]
  float* ksum = (float*)ws;  ws += (size_t)64 * 64 * 4;           // 16 KB

  (void)hipMemsetAsync(kvT, 0, (size_t)64 * 4096 * 4 + (size_t)64 * 64 * 4, stream);

  conv_fused_kernel<<<NXB + 1024, 256, 0, stream>>>(x, Xb, Wq, Wk, Wv, Wo, Wt);
  gemm_bf16<0><<<dim3(12, 64), 512, 0, stream>>>(Xb, Wt, Qb, DM, bq, bk, bv, KT, VT);
  kvk_mfma_kernel<<<dim3(4, 64), 256, 0, stream>>>(KT, VT, kvT, ksum);
  attn_kernel<<<dim3(32, 64), 256, 0, stream>>>(Qb, kvT, ksum, ATT);
  gemm_bf16<1><<<dim3(4, 64), 512, 0, stream>>>(ATT, Wt + (size_t)3 * DM * DM, out, DM,
                                                bo, bo, bo, nullptr, nullptr);
}

// Round 7
// 314.039 us; speedup vs baseline: 1.1123x; 1.1123x over previous
//
#include <hip/hip_runtime.h>

// ---------------------------------------------------------------------------
// LinearAttention: out = (featmap(xWq+bq) @ [K^T V]) / (q . sum K + eps) @ Wo + bo
// featmap(t) = elu(t)+1 = t>0 ? t+1 : exp(t)
// B=4, S=4096, D_MODEL=1024, H=16, DK=64. Inputs fp32; compute in bf16 MFMA.
// R13: overhead round (gemm0/gemm1 FROZEN as A/B anchor).
//     (a) conv_x: 16384 tiny blocks (4KB work each, launch-bound) -> 2048 fat
//         blocks, 8x float4 per thread grid-stride.
//     (b) kvk: non-atomic per-s-block partials kvT4[xb][bh][e*64+d] (+ksum4),
//         plain coalesced stores after LDS reduce; memset dispatch DELETED.
//     (c) attn: sums 4 partials at load (kvT4 4MB L2/L3-resident, +12 VALU).
//     Dispatches 7 -> 5. R12 post-mortem: atomics/conv-merge were neutral;
//     ~130us of iteration time is invisible to top-5 (launch overhead or
//     mis-modeled small kernel) -> cut dispatch count + tiny-block launches.
// ---------------------------------------------------------------------------

typedef __bf16 bf16;
typedef float  f32x4  __attribute__((ext_vector_type(4)));
typedef short  s16x8  __attribute__((ext_vector_type(8)));   // 8 bf16 = 4 VGPRs (MFMA A/B frag)
typedef bf16   bf16x4 __attribute__((ext_vector_type(4)));

#define BATCH 4
#define SEQ   4096
#define DM    1024
#define NH    16
#define DK    64
#define MROWS (BATCH*SEQ)            // 16384
#define EPSV  1e-6f

// async 16B global->LDS DMA. LDS dest is wave-uniform base; HW writes
// base + lane*16.
__device__ __forceinline__ void async_cp16(const bf16* g, bf16* l) {
  __builtin_amdgcn_global_load_lds((const __attribute__((address_space(1))) void*)g,
                                   (__attribute__((address_space(3))) void*)l,
                                   16, 0, 0);
}

// ------------------------------------------------- conv_fused (x + Wt) ------
// bid < 2048: fp32->bf16 cast of x, 8x float4 per thread (grid-stride).
// else: Wt[z*1024+n][k] = Wz[k][n] 64x64 tile transpose via LDS (1024 blocks).
__global__ __launch_bounds__(256) void conv_fused_kernel(const float* __restrict__ x,
                                                         bf16* __restrict__ xb,
                                                         const float* __restrict__ W0,
                                                         const float* __restrict__ W1,
                                                         const float* __restrict__ W2,
                                                         const float* __restrict__ W3,
                                                         bf16* __restrict__ Wt) {
  __shared__ bf16 tt[64][72];                         // [n][k], pad 72
  const int bid = blockIdx.x;
  const int tid = threadIdx.x;
  if (bid < 2048) {                                   // ---- conv_x part
    // total float4 chunks = 16384*1024/4 = 4,194,304 = 2048*256*8
    const int base = bid * 256 + tid;
#pragma unroll
    for (int it = 0; it < 8; ++it) {
      const int idx = base + it * 524288;
      float4 f = *reinterpret_cast<const float4*>(x + (size_t)idx * 4);
      bf16x4 o;
      o[0] = (bf16)f.x; o[1] = (bf16)f.y; o[2] = (bf16)f.z; o[3] = (bf16)f.w;
      *reinterpret_cast<bf16x4*>(xb + (size_t)idx * 4) = o;
    }
    return;
  }
  // ---- conv_w part (1024 blocks: z 0..3, 16x16 tiles)
  const int b2 = bid - 2048;
  const int z = b2 >> 8;
  const float* W = (z == 0) ? W0 : (z == 1) ? W1 : (z == 2) ? W2 : W3;
  const int n0 = (b2 & 15) * 64, k0 = ((b2 >> 4) & 15) * 64;
#pragma unroll
  for (int i = 0; i < 4; ++i) {                       // 1024 float4 chunks (64x16)
    const int c = tid + i * 256;
    const int krow = c >> 4, nch = c & 15;
    float4 f = *reinterpret_cast<const float4*>(W + (size_t)(k0 + krow) * DM + n0 + nch * 4);
    tt[nch * 4 + 0][krow] = (bf16)f.x;
    tt[nch * 4 + 1][krow] = (bf16)f.y;
    tt[nch * 4 + 2][krow] = (bf16)f.z;
    tt[nch * 4 + 3][krow] = (bf16)f.w;
  }
  __syncthreads();
#pragma unroll
  for (int i = 0; i < 2; ++i) {                       // 512 chunks: 64 rows x 8x16B
    const int c = tid + i * 256;
    const int nrow = c >> 3, kch = c & 7;
    *reinterpret_cast<uint4*>(Wt + (size_t)(z * DM + n0 + nrow) * DM + k0 + kch * 8) =
        *reinterpret_cast<const uint4*>(&tt[nrow][kch * 8]);
  }
}

// ------------------------------------------------------------------ GEMM ----
// C[M,N] = A[M,K] * Bt[N,K]^T, K=1024. 256x256 tile, 8 waves (2Mx4N), BK=64.
// R8 2-barrier-per-tile main loop. M-slab XCD swizzle. FROZEN since R11.
// MODE 0: part0 -> Qb (featmap, ldc), part1 -> KT transposed (featmap),
//         part2 -> VT transposed. MODE 1: bias -> fp32 out.
template <int MODE>
__global__ __launch_bounds__(512, 2) void gemm_bf16(const bf16* __restrict__ A,
                                                    const bf16* __restrict__ Bt,
                                                    void* __restrict__ Cout, int ldc,
                                                    const float* __restrict__ b0,
                                                    const float* __restrict__ b1,
                                                    const float* __restrict__ b2,
                                                    bf16* __restrict__ kt,
                                                    bf16* __restrict__ vt) {
  constexpr int K  = 1024;
  constexpr int BK = 64;
  constexpr int NT = K / BK;                          // 16 K-tiles
  __shared__ __align__(16) char smem[131072];         // A:2x32K | B:2x32K (dbuf)

  const int tid  = threadIdx.x;
  const int wv   = tid >> 6, lane = tid & 63;
  const int quad = lane >> 4, l16 = lane & 15;
  const int swk  = l16 & 7;                           // read-side swizzle key

  // M-slab XCD swizzle: hw wgid w -> XCD (w&7) owns M-tiles 8k..8k+7
  // (4MB A-slab, L2-resident). Bijective: w = k + 8*(bx*8 + (by&7)).
  const int w = blockIdx.y * gridDim.x + blockIdx.x;
  const int j = w >> 3;
  const int bm0 = (((w & 7) << 3) + (j & 7)) << 8;    // M-tile (64 total)
  const int bn0 = (j >> 3) << 8;                      // N-tile

  const int wm = wv >> 2;                             // 0..1 -> A half (128 rows)
  const int wn = wv & 3;                              // 0..3 -> B 64-row group

  f32x4 acc[8][4] = {};
  s16x8 af[4][2];                                     // A quad frags [mi][ks]
  s16x8 bq[2][2][2];                                  // B frags [qn][ni][ks]

  const int srow = wv * 8 + (lane >> 3);
  const int scol = ((lane & 7) ^ (lane >> 3)) * 8;    // bf16 elements
  const bf16* Ag = A  + (size_t)(bm0 + srow) * K + scol;
  const bf16* Bg = Bt + (size_t)(bn0 + srow) * K + scol;
  const int sbase = wv * 1024;                        // wave-uniform LDS byte off

#define STAGE_A(t_, h_) do {                                                   \
    const bf16* g_ = Ag + (size_t)((h_) * 128) * K + (t_) * BK;                \
    char* l_ = smem + ((t_) & 1) * 32768 + (h_) * 16384 + sbase;               \
    async_cp16(g_, (bf16*)l_);                                                 \
    async_cp16(g_ + (size_t)64 * K, (bf16*)(l_ + 8192));                       \
  } while (0)
#define STAGE_B(t_, h_) do {                                                   \
    const bf16* g_ = Bg + (size_t)((h_) * 128) * K + (t_) * BK;                \
    char* l_ = smem + 65536 + ((t_) & 1) * 32768 + (h_) * 16384 + sbase;       \
    async_cp16(g_, (bf16*)l_);                                                 \
    async_cp16(g_ + (size_t)64 * K, (bf16*)(l_ + 8192));                       \
  } while (0)
#define LDA(pb_, qm_) do {                                                     \
    const char* ab_ = smem + (pb_) * 32768 +                                   \
        (size_t)(wm * 128 + (qm_) * 64 + l16) * 128;                           \
    _Pragma("unroll") for (int mi = 0; mi < 4; ++mi)                           \
      _Pragma("unroll") for (int ks = 0; ks < 2; ++ks)                         \
        af[mi][ks] = *reinterpret_cast<const s16x8*>(                          \
            ab_ + mi * 2048 + (((ks * 4 + quad) ^ swk) << 4));                 \
  } while (0)
#define LDB(pb_, qn_) do {                                                     \
    const char* bb_ = smem + 65536 + (pb_) * 32768 +                           \
        (size_t)(wn * 64 + (qn_) * 32 + l16) * 128;                            \
    _Pragma("unroll") for (int ni = 0; ni < 2; ++ni)                           \
      _Pragma("unroll") for (int ks = 0; ks < 2; ++ks)                         \
        bq[qn_][ni][ks] = *reinterpret_cast<const s16x8*>(                     \
            bb_ + ni * 2048 + (((ks * 4 + quad) ^ swk) << 4));                 \
  } while (0)
#define MFMA_Q(qm_, qn_) do {                                                  \
    _Pragma("unroll") for (int mi = 0; mi < 4; ++mi)                           \
      _Pragma("unroll") for (int ni = 0; ni < 2; ++ni)                         \
        _Pragma("unroll") for (int ks = 0; ks < 2; ++ks)                       \
          acc[(qm_) * 4 + mi][(qn_) * 2 + ni] =                                \
              __builtin_amdgcn_mfma_f32_16x16x32_bf16(                         \
                  af[mi][ks], bq[qn_][ni][ks],                                 \
                  acc[(qm_) * 4 + mi][(qn_) * 2 + ni], 0, 0, 0);               \
  } while (0)

  // prologue: tile0 full (8 ops) + tile1 h0 (4 ops); wait tile0 landed.
  STAGE_B(0, 0); STAGE_A(0, 0); STAGE_B(0, 1); STAGE_A(0, 1);
  STAGE_B(1, 0); STAGE_A(1, 0);
  asm volatile("s_waitcnt vmcnt(4)");                 // oldest 8 (tile0) retired
  __builtin_amdgcn_s_barrier();
  __builtin_amdgcn_sched_barrier(0);
  LDA(0, 0); LDB(0, 0); LDB(0, 1);                    // pre-reads tile0
  __builtin_amdgcn_sched_barrier(0);

#pragma unroll 2
  for (int t = 0; t < NT; ++t) {
    const int p = t & 1;
    // ---- cluster 0: quadrants (0,0),(0,1) on A0; prefetch B-h1(t+1) -> p^1
    if (t + 1 < NT) STAGE_B(t + 1, 1);
    asm volatile("s_waitcnt lgkmcnt(0)");
    __builtin_amdgcn_sched_barrier(0);
    __builtin_amdgcn_s_setprio(1);
    MFMA_Q(0, 0); MFMA_Q(0, 1);
    __builtin_amdgcn_s_setprio(0);
    LDA(p, 1);                                        // A1 reads run under other waves' MFMA
    __builtin_amdgcn_sched_barrier(0);
    // ---- cluster 1: quadrants (1,0),(1,1) on A1; prefetch A-h1(t+1) -> p^1
    if (t + 1 < NT) STAGE_A(t + 1, 1);
    asm volatile("s_waitcnt lgkmcnt(0)");
    __builtin_amdgcn_sched_barrier(0);
    __builtin_amdgcn_s_setprio(1);
    MFMA_Q(1, 0); MFMA_Q(1, 1);
    __builtin_amdgcn_s_setprio(0);
    __builtin_amdgcn_s_barrier();                     // all reads of buffer p done
    __builtin_amdgcn_sched_barrier(0);
    if (t + 2 < NT) { STAGE_B(t + 2, 0); STAGE_A(t + 2, 0); }  // -> p (safe)
    if (t + 1 < NT) {
      if (t + 2 < NT) asm volatile("s_waitcnt vmcnt(4)");  // all t+1 landed
      else            asm volatile("s_waitcnt vmcnt(0)");  // tail drain
      __builtin_amdgcn_s_barrier();                   // everyone's t+1 stages visible
      __builtin_amdgcn_sched_barrier(0);
      LDA(p ^ 1, 0); LDB(p ^ 1, 0); LDB(p ^ 1, 1);    // pre-reads tile t+1
      __builtin_amdgcn_sched_barrier(0);
    }
  }

  // epilogue: per-wave 16 KB LDS slice (no cross-wave sync; last tile's
  // post-cluster-1 barrier guarantees all waves drained their LDS reads).
  // D layout: col = l16 (N side), row = quad*4 + reg (M side).
  if (MODE == 0) {
    const int part = bn0 >> 10;                       // 0=q 1=k 2=v
    if (part == 0) {
      // Q: normal orientation -> Qb [16384][1024] bf16
      bf16* C = (bf16*)Cout;
      bf16 (*Cw)[64] = (bf16(*)[64])(smem + wv * 16384);
#pragma unroll
      for (int ni = 0; ni < 4; ++ni) {
        const int n_l = ni * 16 + l16;
        const float bias = b0[bn0 + wn * 64 + n_l];
#pragma unroll
        for (int mi = 0; mi < 8; ++mi)
#pragma unroll
          for (int r = 0; r < 4; ++r) {
            float v = acc[mi][ni][r] + bias;
            v = (v > 0.f) ? (v + 1.f) : __expf(v);    // elu+1
            const int row = mi * 16 + quad * 4 + r;
            Cw[row][n_l ^ ((row & 7) << 3)] = (bf16)v;
          }
      }
#pragma unroll
      for (int i = 0; i < 16; ++i) {                  // coalesced 16B stores
        const int row = i * 8 + (lane >> 3), ch = lane & 7;
        *reinterpret_cast<uint4*>(C + (size_t)(bm0 + wm * 128 + row) * ldc +
                                  bn0 + wn * 64 + ch * 8) =
            *reinterpret_cast<const uint4*>(&Cw[row][(ch ^ (row & 7)) * 8]);
      }
    } else {
      // K/V: transposed -> T[bh][d 0..63][s], per-wave LDS transpose.
      bf16* T = (part == 1) ? kt : vt;
      const float* bp = (part == 1) ? b1 : b2;
      const int b  = bm0 >> 12;                       // batch (no straddle)
      const int h  = ((bn0 & 1023) >> 6) + wn;        // wave's 64 cols = 1 head
      const int s_loc = (bm0 & 4095) + wm * 128;
      bf16* base = T + (size_t)(b * 16 + h) * 64 * 4096 + s_loc;
      char* sl = smem + wv * 16384;                   // [64 d][128 s] bf16, XOR-16B swz
#pragma unroll
      for (int ni = 0; ni < 4; ++ni) {
        const int d = ni * 16 + l16;
        const float bias = bp[(bn0 + wn * 64 + d) & 1023];
#pragma unroll
        for (int mi = 0; mi < 8; ++mi) {
          bf16x4 o;
#pragma unroll
          for (int r = 0; r < 4; ++r) {
            float v = acc[mi][ni][r] + bias;
            if (part == 1) v = (v > 0.f) ? (v + 1.f) : __expf(v);  // K featmap
            o[r] = (bf16)v;
          }
          const int sb = mi * 32 + quad * 8;          // byte offset of s*2 (8B-aligned)
          *reinterpret_cast<uint2*>(sl + d * 256 + (sb ^ ((d & 7) << 4))) =
              *reinterpret_cast<const uint2*>(&o);
        }
      }
      // per-wave slice: no barrier. Coalesced rows: d-row = 128 s = 256 B.
#pragma unroll
      for (int i = 0; i < 16; ++i) {
        const int d = i * 4 + (lane >> 4), ch = l16;  // 16B chunk = 8 s
        const uint4 val = *reinterpret_cast<const uint4*>(
            sl + d * 256 + ((ch * 16) ^ ((d & 7) << 4)));
        *reinterpret_cast<uint4*>(base + (size_t)d * 4096 + ch * 8) = val;
      }
    }
  } else {
    float* C = (float*)Cout;
    float (*Cwf)[64] = (float(*)[64])(smem + wv * 16384);
#pragma unroll
    for (int h = 0; h < 2; ++h) {                     // two 64-row passes
#pragma unroll
      for (int ni = 0; ni < 4; ++ni) {
        const int n_l = ni * 16 + l16;
        const float bias = b0[bn0 + wn * 64 + n_l];
#pragma unroll
        for (int mi = 0; mi < 4; ++mi)
#pragma unroll
          for (int r = 0; r < 4; ++r) {
            const int row = mi * 16 + quad * 4 + r;
            Cwf[row][n_l ^ ((row & 7) << 2)] = acc[h * 4 + mi][ni][r] + bias;
          }
      }
#pragma unroll
      for (int i = 0; i < 16; ++i) {                  // coalesced float4 stores
        const int row = i * 4 + (lane >> 4), ch = lane & 15;
        *reinterpret_cast<float4*>(C + (size_t)(bm0 + wm * 128 + h * 64 + row) * ldc +
                                   bn0 + wn * 64 + ch * 4) =
            *reinterpret_cast<const float4*>(&Cwf[row][(ch ^ (row & 7)) * 4]);
      }
    }
  }
#undef STAGE_A
#undef STAGE_B
#undef LDA
#undef LDB
#undef MFMA_Q
}

// -------------------------------------------------------------- kvk_mfma ----
// Partial kv per s-block, NON-ATOMIC: kvT4[xb][bh][e*64+d] = sum over this
// block's 1024 s of V[s,e]*K[s,d] (MFMA on transposed operands); ksum4 same.
// grid (4,64) = 1 block/CU; cross-wave reduce via LDS 'red', then plain
// coalesced float4 stores. No memset needed; attn sums the 4 partials.
__global__ __launch_bounds__(256) void kvk_mfma_kernel(const bf16* __restrict__ KT,
                                                       const bf16* __restrict__ VT,
                                                       float* __restrict__ kvT4,
                                                       float* __restrict__ ksum4) {
  __shared__ bf16 Ks[64][136];       // [d][s], pad 136
  __shared__ bf16 Vs[64][136];       // [e][s]
  __shared__ float red[4][4096];     // per-wave partials [wv][e*64+d]
  const int bh = blockIdx.y;
  const int tid = threadIdx.x;
  const int wv = tid >> 6, lane = tid & 63;
  const int quad = lane >> 4, l16 = lane & 15;
  const size_t tb = (size_t)bh * 64 * 4096;
  const int s0b = blockIdx.x * 1024;

  f32x4 acc[4][4] = {};
  float ksp[4] = {};                 // partial ksum for rows (tid>>4)+16i

  for (int cc = 0; cc < 8; ++cc) {
    const int s0 = s0b + cc * 128;
    __syncthreads();                 // prev-iter LDS reads done before restage
#pragma unroll
    for (int i = 0; i < 4; ++i) {
      const int c = tid + i * 256;
      const int row = c >> 4, ch = c & 15;
      const size_t go = tb + (size_t)row * 4096 + s0 + ch * 8;
      uint4 kk = *reinterpret_cast<const uint4*>(KT + go);
      *reinterpret_cast<uint4*>(&Ks[row][ch * 8]) = kk;
      *reinterpret_cast<uint4*>(&Vs[row][ch * 8]) =
          *reinterpret_cast<const uint4*>(VT + go);
      const bf16* kp = reinterpret_cast<const bf16*>(&kk);
      float t = 0.f;
#pragma unroll
      for (int jj = 0; jj < 8; ++jj) t += (float)kp[jj];
      ksp[i] += t;
    }
    __syncthreads();
    const int kb = wv * 32 + quad * 8;   // wave k-slice + frag quad offset
    s16x8 vfr[4], kfr[4];
#pragma unroll
    for (int mi = 0; mi < 4; ++mi) {
      vfr[mi] = *reinterpret_cast<const s16x8*>(&Vs[mi * 16 + l16][kb]);
      kfr[mi] = *reinterpret_cast<const s16x8*>(&Ks[mi * 16 + l16][kb]);
    }
#pragma unroll
    for (int mi = 0; mi < 4; ++mi)
#pragma unroll
      for (int ni = 0; ni < 4; ++ni)
        acc[mi][ni] = __builtin_amdgcn_mfma_f32_16x16x32_bf16(vfr[mi], kfr[ni],
                                                              acc[mi][ni], 0, 0, 0);
  }
  // cross-wave reduce: D layout row(e)=quad*4+r (+16mi), col(d)=l16 (+16ni)
#pragma unroll
  for (int mi = 0; mi < 4; ++mi)
#pragma unroll
    for (int ni = 0; ni < 4; ++ni)
#pragma unroll
      for (int r = 0; r < 4; ++r)
        red[wv][(mi * 16 + quad * 4 + r) * 64 + ni * 16 + l16] = acc[mi][ni][r];
  __syncthreads();
  float* outp = kvT4 + ((size_t)blockIdx.x * 64 + bh) * 4096;
#pragma unroll
  for (int jj = 0; jj < 4; ++jj) {   // thread sums 16 cells (4 x float4)
    const int c0 = tid * 16 + jj * 4;
    const float4 s0 = *reinterpret_cast<const float4*>(&red[0][c0]);
    const float4 s1 = *reinterpret_cast<const float4*>(&red[1][c0]);
    const float4 s2 = *reinterpret_cast<const float4*>(&red[2][c0]);
    const float4 s3 = *reinterpret_cast<const float4*>(&red[3][c0]);
    float4 o;
    o.x = s0.x + s1.x + s2.x + s3.x;
    o.y = s0.y + s1.y + s2.y + s3.y;
    o.z = s0.z + s1.z + s2.z + s3.z;
    o.w = s0.w + s1.w + s2.w + s3.w;
    *reinterpret_cast<float4*>(outp + c0) = o;        // plain coalesced store
  }
  // ksum: 16-lane groups share row-set {g+16i}, g = tid>>4
#pragma unroll
  for (int i = 0; i < 4; ++i)
#pragma unroll
    for (int o = 8; o > 0; o >>= 1)
      ksp[i] += __shfl_down(ksp[i], o, 16);
  if (l16 == 0) {
    const int g = tid >> 4;
#pragma unroll
    for (int i = 0; i < 4; ++i)
      ksum4[((size_t)blockIdx.x * 64 + bh) * 64 + g + 16 * i] = ksp[i];
  }
}

// ------------------------------------------------------------------ attn ----
// ATT[b,s, h*64+e] = (sum_d q[s,d]*kv[e,d]) / (q[s,:].ksum + eps)   (bf16 out)
// kv = sum of 4 kvT4 partials (L2/L3-resident). MFMA: P^T[e,s] = kv(A) @ q(Bt).
__global__ __launch_bounds__(256) void attn_kernel(const bf16* __restrict__ Qb,
                                                   const float* __restrict__ kvT4,
                                                   const float* __restrict__ ksum4,
                                                   bf16* __restrict__ ATT) {
  __shared__ bf16 qs[128][72];       // [s][d], pad 72
  __shared__ bf16 kvs[64][72];       // [e][d] bf16
  __shared__ bf16 Ps[128][72];       // [s][e] scaled result
  __shared__ float zr[128];
  __shared__ float kss[64];
  const int bh = blockIdx.y;
  const int b = bh >> 4, h = bh & 15;
  const int s0 = blockIdx.x * 128;
  const int tid = threadIdx.x, wave = tid >> 6, lane = tid & 63;
  const int quad = lane >> 4, l16 = lane & 15;
  const size_t base = (size_t)b * SEQ * DM;
  const int colQ = h * 64;

#pragma unroll
  for (int i = 0; i < 4; ++i) {      // stage q tile 128x64
    const int c = tid + i * 256;
    const int row = c >> 3, off = (c & 7) * 8;
    *reinterpret_cast<uint4*>(&qs[row][off]) =
        *reinterpret_cast<const uint4*>(Qb + base + (size_t)(s0 + row) * DM + colQ + off);
  }
  const float* kv0 = kvT4 + (size_t)bh * 4096;        // + xb*64*4096 per partial
#pragma unroll
  for (int i = 0; i < 4; ++i) {      // stage kv 64x64: sum 4 partials -> bf16
    const int c = tid + i * 256;
    const int row = c >> 4, off = (c & 15) * 4;
    const int lin = row * 64 + off;
    float4 f0 = *reinterpret_cast<const float4*>(kv0 + lin);
    float4 f1 = *reinterpret_cast<const float4*>(kv0 + 64 * 4096 + lin);
    float4 f2 = *reinterpret_cast<const float4*>(kv0 + 2 * 64 * 4096 + lin);
    float4 f3 = *reinterpret_cast<const float4*>(kv0 + 3 * 64 * 4096 + lin);
    bf16x4 o;
    o[0] = (bf16)(f0.x + f1.x + f2.x + f3.x);
    o[1] = (bf16)(f0.y + f1.y + f2.y + f3.y);
    o[2] = (bf16)(f0.z + f1.z + f2.z + f3.z);
    o[3] = (bf16)(f0.w + f1.w + f2.w + f3.w);
    *reinterpret_cast<bf16x4*>(&kvs[row][off]) = o;
  }
  if (tid < 64) {
    const float* ks0 = ksum4 + (size_t)bh * 64 + tid;
    kss[tid] = ks0[0] + ks0[64 * 64] + ks0[2 * 64 * 64] + ks0[3 * 64 * 64];
  }
  __syncthreads();

  if (tid < 128) {                   // zr = 1/(q.ksum + eps) per row
    float z = 0.f;
#pragma unroll
    for (int d = 0; d < 64; d += 4) {
      bf16x4 q4 = *reinterpret_cast<const bf16x4*>(&qs[tid][d]);
      z += (float)q4[0] * kss[d] + (float)q4[1] * kss[d + 1] +
           (float)q4[2] * kss[d + 2] + (float)q4[3] * kss[d + 3];
    }
    zr[tid] = 1.0f / (z + EPSV);
  }
  __syncthreads();

  const int wn = wave * 32;
  f32x4 pacc[4][2] = {};
#pragma unroll
  for (int ks = 0; ks < 2; ++ks) {
    s16x8 af[4], bf2[2];
#pragma unroll
    for (int mi = 0; mi < 4; ++mi)
      af[mi] = *reinterpret_cast<const s16x8*>(&kvs[mi * 16 + l16][ks * 32 + quad * 8]);
#pragma unroll
    for (int ni = 0; ni < 2; ++ni)
      bf2[ni] = *reinterpret_cast<const s16x8*>(&qs[wn + ni * 16 + l16][ks * 32 + quad * 8]);
#pragma unroll
    for (int mi = 0; mi < 4; ++mi)
#pragma unroll
      for (int ni = 0; ni < 2; ++ni)
        pacc[mi][ni] = __builtin_amdgcn_mfma_f32_16x16x32_bf16(af[mi], bf2[ni],
                                                               pacc[mi][ni], 0, 0, 0);
  }
#pragma unroll
  for (int ni = 0; ni < 2; ++ni) {
    const int s = wn + ni * 16 + l16;
    const float zi = zr[s];
#pragma unroll
    for (int mi = 0; mi < 4; ++mi) {
      bf16x4 o;
#pragma unroll
      for (int r = 0; r < 4; ++r) o[r] = (bf16)(pacc[mi][ni][r] * zi);
      *reinterpret_cast<bf16x4*>(&Ps[s][mi * 16 + quad * 4]) = o;
    }
  }
  __syncthreads();
#pragma unroll
  for (int i = 0; i < 4; ++i) {      // coalesced 16B stores
    const int c = tid + i * 256;
    const int row = c >> 3, ch = c & 7;
    *reinterpret_cast<uint4*>(ATT + ((size_t)b * SEQ + s0 + row) * DM + h * 64 + ch * 8) =
        *reinterpret_cast<const uint4*>(&Ps[row][ch * 8]);
  }
}

// ---------------------------------------------------------------- launch ----
extern "C" void kernel_launch(void* const* d_in, const int* in_sizes, int n_in,
                              void* d_out, int out_size, void* d_ws, size_t ws_size,
                              hipStream_t stream) {
  const float* x  = (const float*)d_in[0];
  const float* Wq = (const float*)d_in[1];
  const float* bq = (const float*)d_in[2];
  const float* Wk = (const float*)d_in[3];
  const float* bk = (const float*)d_in[4];
  const float* Wv = (const float*)d_in[5];
  const float* bv = (const float*)d_in[6];
  const float* Wo = (const float*)d_in[7];
  const float* bo = (const float*)d_in[8];
  float* out = (float*)d_out;

  char* ws = (char*)d_ws;
  bf16*  Xb   = (bf16*)ws;   ws += (size_t)MROWS * DM * 2;        // 32 MB
  bf16*  Wt   = (bf16*)ws;   ws += (size_t)4 * DM * DM * 2;       // 8 MB (qkv^T + o^T)
  bf16*  Qb   = (bf16*)ws;   ws += (size_t)MROWS * DM * 2;        // 32 MB
  bf16*  KT   = (bf16*)ws;   ws += (size_t)64 * 64 * 4096 * 2;    // 32 MB [bh][d][s]
  bf16*  VT   = (bf16*)ws;   ws += (size_t)64 * 64 * 4096 * 2;    // 32 MB [bh][e][s]
  bf16*  ATT  = (bf16*)ws;   ws += (size_t)MROWS * DM * 2;        // 32 MB
  float* kvT4 = (float*)ws;  ws += (size_t)4 * 64 * 4096 * 4;     // 4 MB [xb][bh][e*64+d]
  float* ksum4= (float*)ws;  ws += (size_t)4 * 64 * 64 * 4;       // 64 KB

  conv_fused_kernel<<<3072, 256, 0, stream>>>(x, Xb, Wq, Wk, Wv, Wo, Wt);
  gemm_bf16<0><<<dim3(12, 64), 512, 0, stream>>>(Xb, Wt, Qb, DM, bq, bk, bv, KT, VT);
  kvk_mfma_kernel<<<dim3(4, 64), 256, 0, stream>>>(KT, VT, kvT4, ksum4);
  attn_kernel<<<dim3(32, 64), 256, 0, stream>>>(Qb, kvT4, ksum4, ATT);
  gemm_bf16<1><<<dim3(4, 64), 512, 0, stream>>>(ATT, Wt + (size_t)3 * DM * DM, out, DM,
                                                bo, bo, bo, nullptr, nullptr);
}

// Round 8
// 313.103 us; speedup vs baseline: 1.1156x; 1.0030x over previous
//
#include <hip/hip_runtime.h>

// ---------------------------------------------------------------------------
// LinearAttention: out = (featmap(xWq+bq) @ [K^T V]) / (q . sum K + eps) @ Wo + bo
// featmap(t) = elu(t)+1 = t>0 ? t+1 : exp(t)
// B=4, S=4096, D_MODEL=1024, H=16, DK=64. Inputs fp32; compute in bf16 MFMA.
// R14: GEMM register-double-buffered A-fragments (af2). R13 post-mortem: the
//     one remaining full-latency LDS stall per tile was LDA(p,1) issued after
//     cluster-0 MFMA then lgkmcnt(0)-waited. Now A1 reads issue at TILE TOP
//     into af2; cluster-0 gate is counted lgkmcnt(8) (waits only the 16
//     boundary pre-reads, leaves 8 A1 reads in flight); cluster-1's
//     lgkmcnt(0) is near-free (A1 had a full 32-MFMA cluster to land).
//     Ledger: lgkm outstanding at gate = 16 pre + 8 A1 = 24 -> wait-to-8
//     retires exactly the pre-reads. vmcnt ledger unchanged from R8.
//     Everything else frozen (conv_fused / kvk partials / attn / 5 dispatches).
// ---------------------------------------------------------------------------

typedef __bf16 bf16;
typedef float  f32x4  __attribute__((ext_vector_type(4)));
typedef short  s16x8  __attribute__((ext_vector_type(8)));   // 8 bf16 = 4 VGPRs (MFMA A/B frag)
typedef bf16   bf16x4 __attribute__((ext_vector_type(4)));

#define BATCH 4
#define SEQ   4096
#define DM    1024
#define NH    16
#define DK    64
#define MROWS (BATCH*SEQ)            // 16384
#define EPSV  1e-6f

// async 16B global->LDS DMA. LDS dest is wave-uniform base; HW writes
// base + lane*16.
__device__ __forceinline__ void async_cp16(const bf16* g, bf16* l) {
  __builtin_amdgcn_global_load_lds((const __attribute__((address_space(1))) void*)g,
                                   (__attribute__((address_space(3))) void*)l,
                                   16, 0, 0);
}

// ------------------------------------------------- conv_fused (x + Wt) ------
// bid < 2048: fp32->bf16 cast of x, 8x float4 per thread (grid-stride).
// else: Wt[z*1024+n][k] = Wz[k][n] 64x64 tile transpose via LDS (1024 blocks).
__global__ __launch_bounds__(256) void conv_fused_kernel(const float* __restrict__ x,
                                                         bf16* __restrict__ xb,
                                                         const float* __restrict__ W0,
                                                         const float* __restrict__ W1,
                                                         const float* __restrict__ W2,
                                                         const float* __restrict__ W3,
                                                         bf16* __restrict__ Wt) {
  __shared__ bf16 tt[64][72];                         // [n][k], pad 72
  const int bid = blockIdx.x;
  const int tid = threadIdx.x;
  if (bid < 2048) {                                   // ---- conv_x part
    const int base = bid * 256 + tid;
#pragma unroll
    for (int it = 0; it < 8; ++it) {
      const int idx = base + it * 524288;
      float4 f = *reinterpret_cast<const float4*>(x + (size_t)idx * 4);
      bf16x4 o;
      o[0] = (bf16)f.x; o[1] = (bf16)f.y; o[2] = (bf16)f.z; o[3] = (bf16)f.w;
      *reinterpret_cast<bf16x4*>(xb + (size_t)idx * 4) = o;
    }
    return;
  }
  // ---- conv_w part (1024 blocks: z 0..3, 16x16 tiles)
  const int b2 = bid - 2048;
  const int z = b2 >> 8;
  const float* W = (z == 0) ? W0 : (z == 1) ? W1 : (z == 2) ? W2 : W3;
  const int n0 = (b2 & 15) * 64, k0 = ((b2 >> 4) & 15) * 64;
#pragma unroll
  for (int i = 0; i < 4; ++i) {                       // 1024 float4 chunks (64x16)
    const int c = tid + i * 256;
    const int krow = c >> 4, nch = c & 15;
    float4 f = *reinterpret_cast<const float4*>(W + (size_t)(k0 + krow) * DM + n0 + nch * 4);
    tt[nch * 4 + 0][krow] = (bf16)f.x;
    tt[nch * 4 + 1][krow] = (bf16)f.y;
    tt[nch * 4 + 2][krow] = (bf16)f.z;
    tt[nch * 4 + 3][krow] = (bf16)f.w;
  }
  __syncthreads();
#pragma unroll
  for (int i = 0; i < 2; ++i) {                       // 512 chunks: 64 rows x 8x16B
    const int c = tid + i * 256;
    const int nrow = c >> 3, kch = c & 7;
    *reinterpret_cast<uint4*>(Wt + (size_t)(z * DM + n0 + nrow) * DM + k0 + kch * 8) =
        *reinterpret_cast<const uint4*>(&tt[nrow][kch * 8]);
  }
}

// ------------------------------------------------------------------ GEMM ----
// C[M,N] = A[M,K] * Bt[N,K]^T, K=1024. 256x256 tile, 8 waves (2Mx4N), BK=64.
// 2-barrier-per-tile loop + reg-dbuf A frags (af2). M-slab XCD swizzle.
// MODE 0: part0 -> Qb (featmap, ldc), part1 -> KT transposed (featmap),
//         part2 -> VT transposed. MODE 1: bias -> fp32 out.
template <int MODE>
__global__ __launch_bounds__(512, 2) void gemm_bf16(const bf16* __restrict__ A,
                                                    const bf16* __restrict__ Bt,
                                                    void* __restrict__ Cout, int ldc,
                                                    const float* __restrict__ b0,
                                                    const float* __restrict__ b1,
                                                    const float* __restrict__ b2,
                                                    bf16* __restrict__ kt,
                                                    bf16* __restrict__ vt) {
  constexpr int K  = 1024;
  constexpr int BK = 64;
  constexpr int NT = K / BK;                          // 16 K-tiles
  __shared__ __align__(16) char smem[131072];         // A:2x32K | B:2x32K (dbuf)

  const int tid  = threadIdx.x;
  const int wv   = tid >> 6, lane = tid & 63;
  const int quad = lane >> 4, l16 = lane & 15;
  const int swk  = l16 & 7;                           // read-side swizzle key

  // M-slab XCD swizzle: hw wgid w -> XCD (w&7) owns M-tiles 8k..8k+7
  // (4MB A-slab, L2-resident). Bijective: w = k + 8*(bx*8 + (by&7)).
  const int w = blockIdx.y * gridDim.x + blockIdx.x;
  const int j = w >> 3;
  const int bm0 = (((w & 7) << 3) + (j & 7)) << 8;    // M-tile (64 total)
  const int bn0 = (j >> 3) << 8;                      // N-tile

  const int wm = wv >> 2;                             // 0..1 -> A half (128 rows)
  const int wn = wv & 3;                              // 0..3 -> B 64-row group

  f32x4 acc[8][4] = {};
  s16x8 af[4][2];                                     // A frags cluster 0 [mi][ks]
  s16x8 af2[4][2];                                    // A frags cluster 1 (reg dbuf)
  s16x8 bq[2][2][2];                                  // B frags [qn][ni][ks]

  const int srow = wv * 8 + (lane >> 3);
  const int scol = ((lane & 7) ^ (lane >> 3)) * 8;    // bf16 elements
  const bf16* Ag = A  + (size_t)(bm0 + srow) * K + scol;
  const bf16* Bg = Bt + (size_t)(bn0 + srow) * K + scol;
  const int sbase = wv * 1024;                        // wave-uniform LDS byte off

#define STAGE_A(t_, h_) do {                                                   \
    const bf16* g_ = Ag + (size_t)((h_) * 128) * K + (t_) * BK;                \
    char* l_ = smem + ((t_) & 1) * 32768 + (h_) * 16384 + sbase;               \
    async_cp16(g_, (bf16*)l_);                                                 \
    async_cp16(g_ + (size_t)64 * K, (bf16*)(l_ + 8192));                       \
  } while (0)
#define STAGE_B(t_, h_) do {                                                   \
    const bf16* g_ = Bg + (size_t)((h_) * 128) * K + (t_) * BK;                \
    char* l_ = smem + 65536 + ((t_) & 1) * 32768 + (h_) * 16384 + sbase;       \
    async_cp16(g_, (bf16*)l_);                                                 \
    async_cp16(g_ + (size_t)64 * K, (bf16*)(l_ + 8192));                       \
  } while (0)
#define LDA_TO(dst_, pb_, qm_) do {                                            \
    const char* ab_ = smem + (pb_) * 32768 +                                   \
        (size_t)(wm * 128 + (qm_) * 64 + l16) * 128;                           \
    _Pragma("unroll") for (int mi = 0; mi < 4; ++mi)                           \
      _Pragma("unroll") for (int ks = 0; ks < 2; ++ks)                         \
        dst_[mi][ks] = *reinterpret_cast<const s16x8*>(                        \
            ab_ + mi * 2048 + (((ks * 4 + quad) ^ swk) << 4));                 \
  } while (0)
#define LDB(pb_, qn_) do {                                                     \
    const char* bb_ = smem + 65536 + (pb_) * 32768 +                           \
        (size_t)(wn * 64 + (qn_) * 32 + l16) * 128;                            \
    _Pragma("unroll") for (int ni = 0; ni < 2; ++ni)                           \
      _Pragma("unroll") for (int ks = 0; ks < 2; ++ks)                         \
        bq[qn_][ni][ks] = *reinterpret_cast<const s16x8*>(                     \
            bb_ + ni * 2048 + (((ks * 4 + quad) ^ swk) << 4));                 \
  } while (0)
#define MFMA_QF(fr_, qm_, qn_) do {                                            \
    _Pragma("unroll") for (int mi = 0; mi < 4; ++mi)                           \
      _Pragma("unroll") for (int ni = 0; ni < 2; ++ni)                         \
        _Pragma("unroll") for (int ks = 0; ks < 2; ++ks)                       \
          acc[(qm_) * 4 + mi][(qn_) * 2 + ni] =                                \
              __builtin_amdgcn_mfma_f32_16x16x32_bf16(                         \
                  fr_[mi][ks], bq[qn_][ni][ks],                                \
                  acc[(qm_) * 4 + mi][(qn_) * 2 + ni], 0, 0, 0);               \
  } while (0)

  // prologue: tile0 full (8 ops) + tile1 h0 (4 ops); wait tile0 landed.
  STAGE_B(0, 0); STAGE_A(0, 0); STAGE_B(0, 1); STAGE_A(0, 1);
  STAGE_B(1, 0); STAGE_A(1, 0);
  asm volatile("s_waitcnt vmcnt(4)");                 // oldest 8 (tile0) retired
  __builtin_amdgcn_s_barrier();
  __builtin_amdgcn_sched_barrier(0);
  LDA_TO(af, 0, 0); LDB(0, 0); LDB(0, 1);             // pre-reads tile0 (16)
  __builtin_amdgcn_sched_barrier(0);

#pragma unroll 2
  for (int t = 0; t < NT; ++t) {
    const int p = t & 1;
    // ---- tile top: issue A1 reads (af2) early; stage B-h1(t+1) -> p^1
    LDA_TO(af2, p, 1);                                // 8 reads, NOT waited yet
    if (t + 1 < NT) STAGE_B(t + 1, 1);
    // gate cluster 0: wait the 16 boundary pre-reads only (A1's 8 in flight)
    asm volatile("s_waitcnt lgkmcnt(8)");
    __builtin_amdgcn_sched_barrier(0);
    __builtin_amdgcn_s_setprio(1);
    MFMA_QF(af, 0, 0); MFMA_QF(af, 0, 1);             // cluster 0 (32 MFMA)
    __builtin_amdgcn_s_setprio(0);
    __builtin_amdgcn_sched_barrier(0);
    // ---- cluster 1: A1 reads had a full MFMA cluster to land
    if (t + 1 < NT) STAGE_A(t + 1, 1);
    asm volatile("s_waitcnt lgkmcnt(0)");
    __builtin_amdgcn_sched_barrier(0);
    __builtin_amdgcn_s_setprio(1);
    MFMA_QF(af2, 1, 0); MFMA_QF(af2, 1, 1);           // cluster 1 (32 MFMA)
    __builtin_amdgcn_s_setprio(0);
    __builtin_amdgcn_s_barrier();                     // all reads of buffer p done
    __builtin_amdgcn_sched_barrier(0);
    if (t + 2 < NT) { STAGE_B(t + 2, 0); STAGE_A(t + 2, 0); }  // -> p (safe)
    if (t + 1 < NT) {
      // vmem outstanding: B/A(t+1,1)[4] + B/A(t+2,0)[4] (h0 of t+1 landed
      // before prior boundary). vmcnt(4) retires all of t+1.
      if (t + 2 < NT) asm volatile("s_waitcnt vmcnt(4)");
      else            asm volatile("s_waitcnt vmcnt(0)");
      __builtin_amdgcn_s_barrier();                   // everyone's t+1 stages visible
      __builtin_amdgcn_sched_barrier(0);
      LDA_TO(af, p ^ 1, 0); LDB(p ^ 1, 0); LDB(p ^ 1, 1);  // pre-reads t+1 (16)
      __builtin_amdgcn_sched_barrier(0);
    }
  }

  // epilogue: per-wave 16 KB LDS slice (no cross-wave sync; last tile's
  // post-cluster-1 barrier guarantees all waves drained their LDS reads).
  // D layout: col = l16 (N side), row = quad*4 + reg (M side).
  if (MODE == 0) {
    const int part = bn0 >> 10;                       // 0=q 1=k 2=v
    if (part == 0) {
      // Q: normal orientation -> Qb [16384][1024] bf16
      bf16* C = (bf16*)Cout;
      bf16 (*Cw)[64] = (bf16(*)[64])(smem + wv * 16384);
#pragma unroll
      for (int ni = 0; ni < 4; ++ni) {
        const int n_l = ni * 16 + l16;
        const float bias = b0[bn0 + wn * 64 + n_l];
#pragma unroll
        for (int mi = 0; mi < 8; ++mi)
#pragma unroll
          for (int r = 0; r < 4; ++r) {
            float v = acc[mi][ni][r] + bias;
            v = (v > 0.f) ? (v + 1.f) : __expf(v);    // elu+1
            const int row = mi * 16 + quad * 4 + r;
            Cw[row][n_l ^ ((row & 7) << 3)] = (bf16)v;
          }
      }
#pragma unroll
      for (int i = 0; i < 16; ++i) {                  // coalesced 16B stores
        const int row = i * 8 + (lane >> 3), ch = lane & 7;
        *reinterpret_cast<uint4*>(C + (size_t)(bm0 + wm * 128 + row) * ldc +
                                  bn0 + wn * 64 + ch * 8) =
            *reinterpret_cast<const uint4*>(&Cw[row][(ch ^ (row & 7)) * 8]);
      }
    } else {
      // K/V: transposed -> T[bh][d 0..63][s], per-wave LDS transpose.
      bf16* T = (part == 1) ? kt : vt;
      const float* bp = (part == 1) ? b1 : b2;
      const int b  = bm0 >> 12;                       // batch (no straddle)
      const int h  = ((bn0 & 1023) >> 6) + wn;        // wave's 64 cols = 1 head
      const int s_loc = (bm0 & 4095) + wm * 128;
      bf16* base = T + (size_t)(b * 16 + h) * 64 * 4096 + s_loc;
      char* sl = smem + wv * 16384;                   // [64 d][128 s] bf16, XOR-16B swz
#pragma unroll
      for (int ni = 0; ni < 4; ++ni) {
        const int d = ni * 16 + l16;
        const float bias = bp[(bn0 + wn * 64 + d) & 1023];
#pragma unroll
        for (int mi = 0; mi < 8; ++mi) {
          bf16x4 o;
#pragma unroll
          for (int r = 0; r < 4; ++r) {
            float v = acc[mi][ni][r] + bias;
            if (part == 1) v = (v > 0.f) ? (v + 1.f) : __expf(v);  // K featmap
            o[r] = (bf16)v;
          }
          const int sb = mi * 32 + quad * 8;          // byte offset of s*2 (8B-aligned)
          *reinterpret_cast<uint2*>(sl + d * 256 + (sb ^ ((d & 7) << 4))) =
              *reinterpret_cast<const uint2*>(&o);
        }
      }
      // per-wave slice: no barrier. Coalesced rows: d-row = 128 s = 256 B.
#pragma unroll
      for (int i = 0; i < 16; ++i) {
        const int d = i * 4 + (lane >> 4), ch = l16;  // 16B chunk = 8 s
        const uint4 val = *reinterpret_cast<const uint4*>(
            sl + d * 256 + ((ch * 16) ^ ((d & 7) << 4)));
        *reinterpret_cast<uint4*>(base + (size_t)d * 4096 + ch * 8) = val;
      }
    }
  } else {
    float* C = (float*)Cout;
    float (*Cwf)[64] = (float(*)[64])(smem + wv * 16384);
#pragma unroll
    for (int h = 0; h < 2; ++h) {                     // two 64-row passes
#pragma unroll
      for (int ni = 0; ni < 4; ++ni) {
        const int n_l = ni * 16 + l16;
        const float bias = b0[bn0 + wn * 64 + n_l];
#pragma unroll
        for (int mi = 0; mi < 4; ++mi)
#pragma unroll
          for (int r = 0; r < 4; ++r) {
            const int row = mi * 16 + quad * 4 + r;
            Cwf[row][n_l ^ ((row & 7) << 2)] = acc[h * 4 + mi][ni][r] + bias;
          }
      }
#pragma unroll
      for (int i = 0; i < 16; ++i) {                  // coalesced float4 stores
        const int row = i * 4 + (lane >> 4), ch = lane & 15;
        *reinterpret_cast<float4*>(C + (size_t)(bm0 + wm * 128 + h * 64 + row) * ldc +
                                   bn0 + wn * 64 + ch * 4) =
            *reinterpret_cast<const float4*>(&Cwf[row][(ch ^ (row & 7)) * 4]);
      }
    }
  }
#undef STAGE_A
#undef STAGE_B
#undef LDA_TO
#undef LDB
#undef MFMA_QF
}

// -------------------------------------------------------------- kvk_mfma ----
// Partial kv per s-block, NON-ATOMIC: kvT4[xb][bh][e*64+d] = sum over this
// block's 1024 s of V[s,e]*K[s,d] (MFMA on transposed operands); ksum4 same.
// grid (4,64) = 1 block/CU; cross-wave reduce via LDS 'red', then plain
// coalesced float4 stores. No memset needed; attn sums the 4 partials.
__global__ __launch_bounds__(256) void kvk_mfma_kernel(const bf16* __restrict__ KT,
                                                       const bf16* __restrict__ VT,
                                                       float* __restrict__ kvT4,
                                                       float* __restrict__ ksum4) {
  __shared__ bf16 Ks[64][136];       // [d][s], pad 136
  __shared__ bf16 Vs[64][136];       // [e][s]
  __shared__ float red[4][4096];     // per-wave partials [wv][e*64+d]
  const int bh = blockIdx.y;
  const int tid = threadIdx.x;
  const int wv = tid >> 6, lane = tid & 63;
  const int quad = lane >> 4, l16 = lane & 15;
  const size_t tb = (size_t)bh * 64 * 4096;
  const int s0b = blockIdx.x * 1024;

  f32x4 acc[4][4] = {};
  float ksp[4] = {};                 // partial ksum for rows (tid>>4)+16i

  for (int cc = 0; cc < 8; ++cc) {
    const int s0 = s0b + cc * 128;
    __syncthreads();                 // prev-iter LDS reads done before restage
#pragma unroll
    for (int i = 0; i < 4; ++i) {
      const int c = tid + i * 256;
      const int row = c >> 4, ch = c & 15;
      const size_t go = tb + (size_t)row * 4096 + s0 + ch * 8;
      uint4 kk = *reinterpret_cast<const uint4*>(KT + go);
      *reinterpret_cast<uint4*>(&Ks[row][ch * 8]) = kk;
      *reinterpret_cast<uint4*>(&Vs[row][ch * 8]) =
          *reinterpret_cast<const uint4*>(VT + go);
      const bf16* kp = reinterpret_cast<const bf16*>(&kk);
      float t = 0.f;
#pragma unroll
      for (int jj = 0; jj < 8; ++jj) t += (float)kp[jj];
      ksp[i] += t;
    }
    __syncthreads();
    const int kb = wv * 32 + quad * 8;   // wave k-slice + frag quad offset
    s16x8 vfr[4], kfr[4];
#pragma unroll
    for (int mi = 0; mi < 4; ++mi) {
      vfr[mi] = *reinterpret_cast<const s16x8*>(&Vs[mi * 16 + l16][kb]);
      kfr[mi] = *reinterpret_cast<const s16x8*>(&Ks[mi * 16 + l16][kb]);
    }
#pragma unroll
    for (int mi = 0; mi < 4; ++mi)
#pragma unroll
      for (int ni = 0; ni < 4; ++ni)
        acc[mi][ni] = __builtin_amdgcn_mfma_f32_16x16x32_bf16(vfr[mi], kfr[ni],
                                                              acc[mi][ni], 0, 0, 0);
  }
  // cross-wave reduce: D layout row(e)=quad*4+r (+16mi), col(d)=l16 (+16ni)
#pragma unroll
  for (int mi = 0; mi < 4; ++mi)
#pragma unroll
    for (int ni = 0; ni < 4; ++ni)
#pragma unroll
      for (int r = 0; r < 4; ++r)
        red[wv][(mi * 16 + quad * 4 + r) * 64 + ni * 16 + l16] = acc[mi][ni][r];
  __syncthreads();
  float* outp = kvT4 + ((size_t)blockIdx.x * 64 + bh) * 4096;
#pragma unroll
  for (int jj = 0; jj < 4; ++jj) {   // thread sums 16 cells (4 x float4)
    const int c0 = tid * 16 + jj * 4;
    const float4 s0 = *reinterpret_cast<const float4*>(&red[0][c0]);
    const float4 s1 = *reinterpret_cast<const float4*>(&red[1][c0]);
    const float4 s2 = *reinterpret_cast<const float4*>(&red[2][c0]);
    const float4 s3 = *reinterpret_cast<const float4*>(&red[3][c0]);
    float4 o;
    o.x = s0.x + s1.x + s2.x + s3.x;
    o.y = s0.y + s1.y + s2.y + s3.y;
    o.z = s0.z + s1.z + s2.z + s3.z;
    o.w = s0.w + s1.w + s2.w + s3.w;
    *reinterpret_cast<float4*>(outp + c0) = o;        // plain coalesced store
  }
  // ksum: 16-lane groups share row-set {g+16i}, g = tid>>4
#pragma unroll
  for (int i = 0; i < 4; ++i)
#pragma unroll
    for (int o = 8; o > 0; o >>= 1)
      ksp[i] += __shfl_down(ksp[i], o, 16);
  if (l16 == 0) {
    const int g = tid >> 4;
#pragma unroll
    for (int i = 0; i < 4; ++i)
      ksum4[((size_t)blockIdx.x * 64 + bh) * 64 + g + 16 * i] = ksp[i];
  }
}

// ------------------------------------------------------------------ attn ----
// ATT[b,s, h*64+e] = (sum_d q[s,d]*kv[e,d]) / (q[s,:].ksum + eps)   (bf16 out)
// kv = sum of 4 kvT4 partials (L2/L3-resident). MFMA: P^T[e,s] = kv(A) @ q(Bt).
__global__ __launch_bounds__(256) void attn_kernel(const bf16* __restrict__ Qb,
                                                   const float* __restrict__ kvT4,
                                                   const float* __restrict__ ksum4,
                                                   bf16* __restrict__ ATT) {
  __shared__ bf16 qs[128][72];       // [s][d], pad 72
  __shared__ bf16 kvs[64][72];       // [e][d] bf16
  __shared__ bf16 Ps[128][72];       // [s][e] scaled result
  __shared__ float zr[128];
  __shared__ float kss[64];
  const int bh = blockIdx.y;
  const int b = bh >> 4, h = bh & 15;
  const int s0 = blockIdx.x * 128;
  const int tid = threadIdx.x, wave = tid >> 6, lane = tid & 63;
  const int quad = lane >> 4, l16 = lane & 15;
  const size_t base = (size_t)b * SEQ * DM;
  const int colQ = h * 64;

#pragma unroll
  for (int i = 0; i < 4; ++i) {      // stage q tile 128x64
    const int c = tid + i * 256;
    const int row = c >> 3, off = (c & 7) * 8;
    *reinterpret_cast<uint4*>(&qs[row][off]) =
        *reinterpret_cast<const uint4*>(Qb + base + (size_t)(s0 + row) * DM + colQ + off);
  }
  const float* kv0 = kvT4 + (size_t)bh * 4096;        // + xb*64*4096 per partial
#pragma unroll
  for (int i = 0; i < 4; ++i) {      // stage kv 64x64: sum 4 partials -> bf16
    const int c = tid + i * 256;
    const int row = c >> 4, off = (c & 15) * 4;
    const int lin = row * 64 + off;
    float4 f0 = *reinterpret_cast<const float4*>(kv0 + lin);
    float4 f1 = *reinterpret_cast<const float4*>(kv0 + 64 * 4096 + lin);
    float4 f2 = *reinterpret_cast<const float4*>(kv0 + 2 * 64 * 4096 + lin);
    float4 f3 = *reinterpret_cast<const float4*>(kv0 + 3 * 64 * 4096 + lin);
    bf16x4 o;
    o[0] = (bf16)(f0.x + f1.x + f2.x + f3.x);
    o[1] = (bf16)(f0.y + f1.y + f2.y + f3.y);
    o[2] = (bf16)(f0.z + f1.z + f2.z + f3.z);
    o[3] = (bf16)(f0.w + f1.w + f2.w + f3.w);
    *reinterpret_cast<bf16x4*>(&kvs[row][off]) = o;
  }
  if (tid < 64) {
    const float* ks0 = ksum4 + (size_t)bh * 64 + tid;
    kss[tid] = ks0[0] + ks0[64 * 64] + ks0[2 * 64 * 64] + ks0[3 * 64 * 64];
  }
  __syncthreads();

  if (tid < 128) {                   // zr = 1/(q.ksum + eps) per row
    float z = 0.f;
#pragma unroll
    for (int d = 0; d < 64; d += 4) {
      bf16x4 q4 = *reinterpret_cast<const bf16x4*>(&qs[tid][d]);
      z += (float)q4[0] * kss[d] + (float)q4[1] * kss[d + 1] +
           (float)q4[2] * kss[d + 2] + (float)q4[3] * kss[d + 3];
    }
    zr[tid] = 1.0f / (z + EPSV);
  }
  __syncthreads();

  const int wn = wave * 32;
  f32x4 pacc[4][2] = {};
#pragma unroll
  for (int ks = 0; ks < 2; ++ks) {
    s16x8 af[4], bf2[2];
#pragma unroll
    for (int mi = 0; mi < 4; ++mi)
      af[mi] = *reinterpret_cast<const s16x8*>(&kvs[mi * 16 + l16][ks * 32 + quad * 8]);
#pragma unroll
    for (int ni = 0; ni < 2; ++ni)
      bf2[ni] = *reinterpret_cast<const s16x8*>(&qs[wn + ni * 16 + l16][ks * 32 + quad * 8]);
#pragma unroll
    for (int mi = 0; mi < 4; ++mi)
#pragma unroll
      for (int ni = 0; ni < 2; ++ni)
        pacc[mi][ni] = __builtin_amdgcn_mfma_f32_16x16x32_bf16(af[mi], bf2[ni],
                                                               pacc[mi][ni], 0, 0, 0);
  }
#pragma unroll
  for (int ni = 0; ni < 2; ++ni) {
    const int s = wn + ni * 16 + l16;
    const float zi = zr[s];
#pragma unroll
    for (int mi = 0; mi < 4; ++mi) {
      bf16x4 o;
#pragma unroll
      for (int r = 0; r < 4; ++r) o[r] = (bf16)(pacc[mi][ni][r] * zi);
      *reinterpret_cast<bf16x4*>(&Ps[s][mi * 16 + quad * 4]) = o;
    }
  }
  __syncthreads();
#pragma unroll
  for (int i = 0; i < 4; ++i) {      // coalesced 16B stores
    const int c = tid + i * 256;
    const int row = c >> 3, ch = c & 7;
    *reinterpret_cast<uint4*>(ATT + ((size_t)b * SEQ + s0 + row) * DM + h * 64 + ch * 8) =
        *reinterpret_cast<const uint4*>(&Ps[row][ch * 8]);
  }
}

// ---------------------------------------------------------------- launch ----
extern "C" void kernel_launch(void* const* d_in, const int* in_sizes, int n_in,
                              void* d_out, int out_size, void* d_ws, size_t ws_size,
                              hipStream_t stream) {
  const float* x  = (const float*)d_in[0];
  const float* Wq = (const float*)d_in[1];
  const float* bq = (const float*)d_in[2];
  const float* Wk = (const float*)d_in[3];
  const float* bk = (const float*)d_in[4];
  const float* Wv = (const float*)d_in[5];
  const float* bv = (const float*)d_in[6];
  const float* Wo = (const float*)d_in[7];
  const float* bo = (const float*)d_in[8];
  float* out = (float*)d_out;

  char* ws = (char*)d_ws;
  bf16*  Xb   = (bf16*)ws;   ws += (size_t)MROWS * DM * 2;        // 32 MB
  bf16*  Wt   = (bf16*)ws;   ws += (size_t)4 * DM * DM * 2;       // 8 MB (qkv^T + o^T)
  bf16*  Qb   = (bf16*)ws;   ws += (size_t)MROWS * DM * 2;        // 32 MB
  bf16*  KT   = (bf16*)ws;   ws += (size_t)64 * 64 * 4096 * 2;    // 32 MB [bh][d][s]
  bf16*  VT   = (bf16*)ws;   ws += (size_t)64 * 64 * 4096 * 2;    // 32 MB [bh][e][s]
  bf16*  ATT  = (bf16*)ws;   ws += (size_t)MROWS * DM * 2;        // 32 MB
  float* kvT4 = (float*)ws;  ws += (size_t)4 * 64 * 4096 * 4;     // 4 MB [xb][bh][e*64+d]
  float* ksum4= (float*)ws;  ws += (size_t)4 * 64 * 64 * 4;       // 64 KB

  conv_fused_kernel<<<3072, 256, 0, stream>>>(x, Xb, Wq, Wk, Wv, Wo, Wt);
  gemm_bf16<0><<<dim3(12, 64), 512, 0, stream>>>(Xb, Wt, Qb, DM, bq, bk, bv, KT, VT);
  kvk_mfma_kernel<<<dim3(4, 64), 256, 0, stream>>>(KT, VT, kvT4, ksum4);
  attn_kernel<<<dim3(32, 64), 256, 0, stream>>>(Qb, kvT4, ksum4, ATT);
  gemm_bf16<1><<<dim3(4, 64), 512, 0, stream>>>(ATT, Wt + (size_t)3 * DM * DM, out, DM,
                                                bo, bo, bo, nullptr, nullptr);
}